// Round 2
// baseline (244.213 us; speedup 1.0000x reference)
//
#include <hip/hip_runtime.h>

// Monotone rational-quadratic spline transform (neural spline flow bin eval).
// inputs [64,4096,128] f32; widths [128,8]; heights [128,8]; derivs [128,9].
// Memory-bound: 268 MB HBM traffic -> ~42us floor @ 6.3 TB/s achievable.

constexpr float TAILF  = 3.0f;
constexpr float EPSF   = 1e-6f;
constexpr int   NB     = 8;
constexpr int   CH     = 128;
constexpr float MIN_BW = 0.01f;
constexpr float MIN_BH = 0.01f;
constexpr float MIN_D  = 0.01f;

// block=256 (4 waves); LDS 36KB -> 4 blocks/CU -> 16 waves/CU.
__global__ __launch_bounds__(256, 4) void rqs_kernel(
    const float* __restrict__ in,
    const float* __restrict__ widths,
    const float* __restrict__ heights,
    const float* __restrict__ derivs,
    float* __restrict__ out, int n4)
{
    // Per-(channel,bin) parameter structs, XOR-swizzled by (c>>2)&7 (== lane&7
    // for the owning lanes) so data-dependent bin gathers spread across all 8
    // LDS bank-groups even when every lane hits the same bin index.
    __shared__ float4 Apar[CH * NB];   // {cwl, 1/bw, delta, d_left}
    __shared__ float4 Bpar[CH * NB];   // {bh, dl+dr-2*delta, chl, 0}
    __shared__ float  Eshared[CH * 8]; // interior width-edges cw[1..7] per ch

    const int tid = threadIdx.x;

    // ---- per-block parameter setup: one thread per channel ----
    if (tid < CH) {
        const int c = tid;
        float cwe[NB + 1], che[NB + 1], dv[NB + 1];

        { // widths -> softmax -> affine -> cumsum -> edges in [-3,3]
            float v[NB];
            float m = -3.4e38f;
            for (int k = 0; k < NB; ++k) { v[k] = widths[c * NB + k]; m = fmaxf(m, v[k]); }
            float s = 0.f;
            for (int k = 0; k < NB; ++k) { v[k] = expf(v[k] - m); s += v[k]; }
            float cum = 0.f;
            cwe[0] = 0.f;
            for (int k = 0; k < NB; ++k) {
                float w = (v[k] / s) * (1.0f - MIN_BW * (float)NB) + MIN_BW;
                cum += w;
                cwe[k + 1] = cum;
            }
            float last = fmaxf(cwe[NB], EPSF);
            for (int k = 0; k <= NB; ++k)
                cwe[k] = 2.0f * TAILF * (cwe[k] / last) - TAILF;
        }
        { // heights -> same pipeline
            float v[NB];
            float m = -3.4e38f;
            for (int k = 0; k < NB; ++k) { v[k] = heights[c * NB + k]; m = fmaxf(m, v[k]); }
            float s = 0.f;
            for (int k = 0; k < NB; ++k) { v[k] = expf(v[k] - m); s += v[k]; }
            float cum = 0.f;
            che[0] = 0.f;
            for (int k = 0; k < NB; ++k) {
                float h = (v[k] / s) * (1.0f - MIN_BH * (float)NB) + MIN_BH;
                cum += h;
                che[k + 1] = cum;
            }
            float last = fmaxf(che[NB], EPSF);
            for (int k = 0; k <= NB; ++k)
                che[k] = 2.0f * TAILF * (che[k] / last) - TAILF;
        }
        // derivatives -> stable softplus + MIN_D (matches jax.nn.softplus)
        for (int k = 0; k <= NB; ++k) {
            float x = derivs[c * (NB + 1) + k];
            dv[k] = fmaxf(x, 0.f) + log1pf(expf(-fabsf(x))) + MIN_D;
        }

        const int swz = (c >> 2) & 7;
        for (int b = 0; b < NB; ++b) {
            float cwl = cwe[b], cwr = cwe[b + 1];
            float chl = che[b], chr = che[b + 1];
            float bw = cwr - cwl, bh = chr - chl;
            float delta  = bh / bw;
            float inv_bw = 1.0f / bw;
            float dl = dv[b], dr = dv[b + 1];
            float dsum = dl + dr - 2.0f * delta;
            int idx = c * NB + (b ^ swz);
            Apar[idx] = make_float4(cwl, inv_bw, delta, dl);
            Bpar[idx] = make_float4(bh, dsum, chl, 0.f);
        }
        for (int k = 0; k < 7; ++k) Eshared[c * 8 + k] = cwe[k + 1];
        Eshared[c * 8 + 7] = TAILF;
    }
    __syncthreads();

    // Each thread owns 4 fixed channels (grid stride is a multiple of 32
    // float4s), so its 7 search edges per channel live in registers (28 VGPR).
    const int gtid = blockIdx.x * blockDim.x + tid;
    const int c0   = 4 * (tid & 31);
    float e[4][7];
    #pragma unroll
    for (int j = 0; j < 4; ++j)
        #pragma unroll
        for (int k = 0; k < 7; ++k)
            e[j][k] = Eshared[(c0 + j) * 8 + k];
    const int swz0 = (c0 >> 2) & 7;

    const float4* __restrict__ in4  = reinterpret_cast<const float4*>(in);
    float4*       __restrict__ out4 = reinterpret_cast<float4*>(out);
    const int stride = gridDim.x * blockDim.x;

    for (int i = gtid; i < n4; i += stride) {
        float4 x4 = in4[i];
        float xs[4] = {x4.x, x4.y, x4.z, x4.w};
        float r[4];
        #pragma unroll
        for (int j = 0; j < 4; ++j) {
            float xo = xs[j];
            float x  = fminf(fmaxf(xo, -TAILF + EPSF), TAILF - EPSF);
            // edge cw[0] = -TAIL is always <= clipped x -> count interior edges
            int b = 0;
            #pragma unroll
            for (int k = 0; k < 7; ++k) b += (x >= e[j][k]) ? 1 : 0;
            int idx = (c0 + j) * NB + (b ^ swz0);
            float4 a  = Apar[idx];
            float4 bp = Bpar[idx];
            float theta = (x - a.x) * a.y;          // (x - cwl) / bw
            theta = fminf(fmaxf(theta, 0.f), 1.f);
            float t1m = theta * (1.f - theta);
            float num = bp.x * (a.z * theta * theta + a.w * t1m);
            float den = a.z + bp.y * t1m;
            float res = bp.z + num / den;
            bool outside = (xo > TAILF) | (xo < -TAILF);
            r[j] = outside ? xo : res;
        }
        out4[i] = make_float4(r[0], r[1], r[2], r[3]);
    }
}

extern "C" void kernel_launch(void* const* d_in, const int* in_sizes, int n_in,
                              void* d_out, int out_size, void* d_ws, size_t ws_size,
                              hipStream_t stream) {
    const float* in      = (const float*)d_in[0];
    const float* widths  = (const float*)d_in[1];
    const float* heights = (const float*)d_in[2];
    const float* derivs  = (const float*)d_in[3];
    float* out = (float*)d_out;

    int n4 = out_size / 4; // 33,554,432 / 4 = 8,388,608 (exactly divisible)
    dim3 grid(1024), block(256); // stride 262144 float4s: multiple of 32 ✓
    hipLaunchKernelGGL(rqs_kernel, grid, block, 0, stream,
                       in, widths, heights, derivs, out, n4);
}